// Round 1
// baseline (88.243 us; speedup 1.0000x reference)
//
#include <hip/hip_runtime.h>
#include <math.h>

namespace {
constexpr int NVEH = 2048;
constexpr int THREADS = 256;
constexpr int EGOS_PER_WAVE = 4;
constexpr int WAVES = THREADS / 64;                     // 4
constexpr int EGOS_PER_BLOCK = WAVES * EGOS_PER_WAVE;   // 16
constexpr int BLOCKS_PER_BATCH = NVEH / EGOS_PER_BLOCK; // 128
}

__global__ __launch_bounds__(THREADS, 4) void idm_kernel(
    const float* __restrict__ state,    // [B, NVEH*5]
    const float* __restrict__ lengths,  // [NVEH]
    const float* __restrict__ v0p, const float* __restrict__ s0p,
    const float* __restrict__ dthp, const float* __restrict__ amaxp,
    const float* __restrict__ bp,
    float* __restrict__ out)            // [B, NVEH]
{
    __shared__ float2 sxy[NVEH];        // 16 KB

    const int b = blockIdx.x / BLOCKS_PER_BATCH;
    const int egoBase = (blockIdx.x % BLOCKS_PER_BATCH) * EGOS_PER_BLOCK;
    const float* __restrict__ st = state + (size_t)b * NVEH * 5;

    // Stage candidate positions (x,y) for this batch into LDS.
    for (int i = threadIdx.x; i < NVEH; i += THREADS) {
        sxy[i] = make_float2(st[i * 5 + 0], st[i * 5 + 1]);
    }
    __syncthreads();

    const int wave = threadIdx.x >> 6;
    const int lane = threadIdx.x & 63;
    const int j0 = egoBase + wave * EGOS_PER_WAVE;

    // Per-ego (4 egos per wave) parameters, broadcast-loaded by every lane.
    float xj[EGOS_PER_WAVE], yj[EGOS_PER_WAVE], vj[EGOS_PER_WAVE];
    float cp[EGOS_PER_WAVE], sp[EGOS_PER_WAVE];
    #pragma unroll
    for (int e = 0; e < EGOS_PER_WAVE; e++) {
        const int j = j0 + e;
        xj[e] = st[j * 5 + 0];
        yj[e] = st[j * 5 + 1];
        vj[e] = st[j * 5 + 2];
        float psi = st[j * 5 + 3];
        float s, c;
        sincosf(psi, &s, &c);
        cp[e] = c; sp[e] = s;
    }

    // cos(20 deg)^2
    const float chalf = 0.93969262078590838f;
    const float c2 = chalf * chalf;

    float minv[EGOS_PER_WAVE];
    int   mini[EGOS_PER_WAVE];
    #pragma unroll
    for (int e = 0; e < EGOS_PER_WAVE; e++) { minv[e] = INFINITY; mini[e] = 0; }

    // Lane-strided sweep over candidates; each loaded candidate serves 4 egos.
    for (int k = 0; k < NVEH / 64; k++) {
        const int i = k * 64 + lane;
        const float2 xy = sxy[i];
        #pragma unroll
        for (int e = 0; e < EGOS_PER_WAVE; e++) {
            const float dx = xy.x - xj[e];
            const float dy = xy.y - yj[e];
            const float proj = dx * cp[e] + dy * sp[e];  // longitudinal dist
            const float dr2 = dx * dx + dy * dy;
            // cone: proj>0 && proj > dr*cos(20deg)  <=>  proj>0 && proj^2 > dr2*c2
            const bool cone = (proj > 0.0f) && (proj * proj > dr2 * c2);
            if (cone && (proj < minv[e])) {  // strict < keeps first occurrence
                minv[e] = proj;
                mini[e] = i;
            }
        }
    }

    // Wave-wide butterfly argmin (value, then lower index on ties — matches
    // jnp.argmin first-occurrence; all-inf case reduces to idx 0).
    #pragma unroll
    for (int e = 0; e < EGOS_PER_WAVE; e++) {
        float v = minv[e];
        int idx = mini[e];
        #pragma unroll
        for (int off = 32; off > 0; off >>= 1) {
            const float ov = __shfl_xor(v, off, 64);
            const int oi = __shfl_xor(idx, off, 64);
            if (ov < v || (ov == v && oi < idx)) { v = ov; idx = oi; }
        }
        minv[e] = v;
        mini[e] = idx;
    }

    if (lane == 0) {
        const float v0v = *v0p;
        const float s0v = *s0p;
        const float dthv = *dthp;
        const float am = *amaxp;
        const float bv = *bp;
        const float inv2sab = 1.0f / (2.0f * sqrtf(am * bv));

        #pragma unroll
        for (int e = 0; e < EGOS_PER_WAVE; e++) {
            const int j = j0 + e;
            const float vE = vj[e];
            const float t = vE / v0v;
            const float t2 = t * t;
            const float action_free = am * (1.0f - t2 * t2);
            float action = action_free;

            const float cnd = minv[e];
            if (cnd < 1.0e30f) {  // finite => leader exists
                const int ind = mini[e];
                const float vl = st[ind * 5 + 2];
                const float pl = st[ind * 5 + 3];
                float sl, cl;
                sincosf(pl, &sl, &cl);
                const float dvx = vl * cl - vE * cp[e];
                const float dvy = vl * sl - vE * sp[e];
                const float ndv = dvx * cp[e] + dvy * sp[e];
                const float sstar = s0v + vE * dthv + vE * ndv * inv2sab;
                const float sal = cnd - lengths[j];
                const float r = sstar / sal;
                action = action_free - am * r * r;
            }
            out[b * NVEH + j] = action;
        }
    }
}

extern "C" void kernel_launch(void* const* d_in, const int* in_sizes, int n_in,
                              void* d_out, int out_size, void* d_ws, size_t ws_size,
                              hipStream_t stream) {
    const float* state   = (const float*)d_in[0];
    const float* lengths = (const float*)d_in[1];
    const float* v0      = (const float*)d_in[2];
    const float* s0      = (const float*)d_in[3];
    const float* dth     = (const float*)d_in[4];
    const float* amax    = (const float*)d_in[5];
    const float* bb      = (const float*)d_in[6];
    float* out = (float*)d_out;

    const int B = in_sizes[0] / (NVEH * 5);   // 8
    dim3 grid(B * BLOCKS_PER_BATCH);          // 1024 blocks
    idm_kernel<<<grid, THREADS, 0, stream>>>(state, lengths, v0, s0, dth, amax, bb, out);
}

// Round 2
// 82.155 us; speedup vs baseline: 1.0741x; 1.0741x over previous
//
#include <hip/hip_runtime.h>
#include <math.h>

typedef float v2f __attribute__((ext_vector_type(2)));

namespace {
constexpr int NVEH = 2048;
constexpr int HALF = NVEH / 2;                          // 1024
constexpr int THREADS = 256;
constexpr int WAVES = THREADS / 64;                     // 4
constexpr int EGOS_PER_WAVE = 8;
constexpr int EGOS_PER_BLOCK = WAVES * EGOS_PER_WAVE;   // 32
constexpr int BLOCKS_PER_BATCH = NVEH / EGOS_PER_BLOCK; // 64
constexpr int ITERS = HALF / 64;                        // 16
}

__global__ __launch_bounds__(THREADS, 2) void idm_kernel(
    const float* __restrict__ state,    // [B, NVEH*5]
    const float* __restrict__ lengths,  // [NVEH]
    const float* __restrict__ v0p, const float* __restrict__ s0p,
    const float* __restrict__ dthp, const float* __restrict__ amaxp,
    const float* __restrict__ bp,
    float* __restrict__ out)            // [B, NVEH]
{
    // Candidate (x,y) pairs: entry i holds (x_i, y_i, x_{i+1024}, y_{i+1024})
    // -> one ds_read_b128 feeds two packed-fp32 candidate slots.
    __shared__ float4 sxy[HALF];        // 16 KB

    const int b = blockIdx.x / BLOCKS_PER_BATCH;
    const int egoBase = (blockIdx.x % BLOCKS_PER_BATCH) * EGOS_PER_BLOCK;
    const float* __restrict__ st = state + (size_t)b * NVEH * 5;

    for (int i = threadIdx.x; i < HALF; i += THREADS) {
        sxy[i] = make_float4(st[i * 5 + 0], st[i * 5 + 1],
                             st[(i + HALF) * 5 + 0], st[(i + HALF) * 5 + 1]);
    }
    __syncthreads();

    const int wave = threadIdx.x >> 6;
    const int lane = threadIdx.x & 63;
    const int j0 = egoBase + wave * EGOS_PER_WAVE;

    // Lane-parallel ego setup: lane (e mod 8) owns ego j0+e's sincos; one
    // wave-wide sincos instead of 8 redundant ones. Broadcast via shfl.
    float ex, ey, ev, ec, es;
    {
        const int j = j0 + (lane & 7);
        ex = st[j * 5 + 0];
        ey = st[j * 5 + 1];
        ev = st[j * 5 + 2];
        const float ps = st[j * 5 + 3];
        sincosf(ps, &es, &ec);
    }

    float xj[EGOS_PER_WAVE], yj[EGOS_PER_WAVE], cp[EGOS_PER_WAVE], sp[EGOS_PER_WAVE];
    #pragma unroll
    for (int e = 0; e < EGOS_PER_WAVE; e++) {
        xj[e] = __shfl(ex, e, 64);
        yj[e] = __shfl(ey, e, 64);
        cp[e] = __shfl(ec, e, 64);
        sp[e] = __shfl(es, e, 64);
    }

    const float chalf = 0.93969262078590838f;  // cos(20 deg)
    const float c2 = chalf * chalf;

    float minv[EGOS_PER_WAVE];
    int   mini[EGOS_PER_WAVE];
    #pragma unroll
    for (int e = 0; e < EGOS_PER_WAVE; e++) { minv[e] = INFINITY; mini[e] = 0; }

    // Packed-fp32 inner loop: 2 candidates/lane/iter, 8 egos amortize the LDS read.
    for (int k = 0; k < ITERS; k++) {
        const int i0 = k * 64 + lane;
        const float4 c = sxy[i0];
        const v2f xi = {c.x, c.z};
        const v2f yi = {c.y, c.w};
        #pragma unroll
        for (int e = 0; e < EGOS_PER_WAVE; e++) {
            const v2f dx = xi - xj[e];
            const v2f dy = yi - yj[e];
            const v2f proj = dx * cp[e] + dy * sp[e];   // longitudinal dist
            const v2f dr2 = dx * dx + dy * dy;
            const v2f q = proj * proj - dr2 * c2;       // >0 <=> |delpsi| < 20deg
            if (proj.x > 0.0f && q.x > 0.0f && proj.x < minv[e]) {
                minv[e] = proj.x; mini[e] = i0;
            }
            if (proj.y > 0.0f && q.y > 0.0f && proj.y < minv[e]) {
                minv[e] = proj.y; mini[e] = i0 + HALF;
            }
        }
    }

    // Wave-wide butterfly argmin, lower index wins ties.
    #pragma unroll
    for (int e = 0; e < EGOS_PER_WAVE; e++) {
        float v = minv[e];
        int idx = mini[e];
        #pragma unroll
        for (int off = 32; off > 0; off >>= 1) {
            const float ov = __shfl_xor(v, off, 64);
            const int oi = __shfl_xor(idx, off, 64);
            if (ov < v || (ov == v && oi < idx)) { v = ov; idx = oi; }
        }
        minv[e] = v;
        mini[e] = idx;
    }

    // Epilogue: lane e (<8) finishes ego j0+e; sincos for all 8 leaders in parallel.
    float cnd = minv[0];
    int ind = mini[0];
    #pragma unroll
    for (int e = 1; e < EGOS_PER_WAVE; e++) {
        if ((lane & 7) == e) { cnd = minv[e]; ind = mini[e]; }
    }

    if (lane < EGOS_PER_WAVE) {
        const int j = j0 + lane;
        const float v0v = *v0p;
        const float s0v = *s0p;
        const float dthv = *dthp;
        const float am = *amaxp;
        const float bv = *bp;

        const float t = ev / v0v;
        const float t2 = t * t;
        const float action_free = am * (1.0f - t2 * t2);
        float action = action_free;

        if (cnd < 1.0e30f) {  // finite => leader exists
            const float vl = st[ind * 5 + 2];
            const float pl = st[ind * 5 + 3];
            float sl, cl;
            sincosf(pl, &sl, &cl);
            const float dvx = vl * cl - ev * ec;
            const float dvy = vl * sl - ev * es;
            const float ndv = dvx * ec + dvy * es;
            const float sstar = s0v + ev * dthv + ev * ndv / (2.0f * sqrtf(am * bv));
            const float sal = cnd - lengths[j];
            const float r = sstar / sal;
            action = action_free - am * r * r;
        }
        out[b * NVEH + j] = action;
    }
}

extern "C" void kernel_launch(void* const* d_in, const int* in_sizes, int n_in,
                              void* d_out, int out_size, void* d_ws, size_t ws_size,
                              hipStream_t stream) {
    const float* state   = (const float*)d_in[0];
    const float* lengths = (const float*)d_in[1];
    const float* v0      = (const float*)d_in[2];
    const float* s0      = (const float*)d_in[3];
    const float* dth     = (const float*)d_in[4];
    const float* amax    = (const float*)d_in[5];
    const float* bb      = (const float*)d_in[6];
    float* out = (float*)d_out;

    const int B = in_sizes[0] / (NVEH * 5);   // 8
    dim3 grid(B * BLOCKS_PER_BATCH);          // 512 blocks = 2 per CU
    idm_kernel<<<grid, THREADS, 0, stream>>>(state, lengths, v0, s0, dth, amax, bb, out);
}